// Round 3
// baseline (384.020 us; speedup 1.0000x reference)
//
#include <hip/hip_runtime.h>
#include <stdint.h>

// ---------------------------------------------------------------------------
// RowParallelLinearSparse: out[M,N] = x[M,K] · (W ⊙ nm_mask(W))[N,K]^T + bias
// M=16384 (S*B), N=O=2048, K=H=2048.  bf16 MFMA.
//
// GEMM v3: 128x256 tile, BK=32, 4 waves (1Mx4N, per-wave 128x64 C), ring-3
// LDS (72 KiB -> 2 blocks/CU for cross-block barrier-overlap), counted
// s_waitcnt vmcnt(6), 2-phase per K-tile {reads ∥ stage → bar → lgkm(0) →
// 16-MFMA setprio cluster → bar}, XOR-swizzled LDS (conflict-free, verified:
// SQ_LDS_BANK_CONFLICT=0), XCD-ownership N-columns (N/256==8==#XCDs).
//
// Ring-3 race-freedom: STAGE(t+2)->buf[(t+2)%3]=buf[(t-1)%3] issues in tile
// t ph0, which every wave reaches only after tile t-1's end barrier; all
// waves' ds_reads of buf[(t-1)%3] are register-complete before that barrier
// (lgkm drain precedes MFMA precedes barrier). Loads land only after issue.
// Tile-t data ready: vmcnt(6)/(0) at tile t-1 ph1 drains tile t's 6 loads,
// then the barrier makes it a block-wide rendezvous.
// ---------------------------------------------------------------------------

typedef short  bf16x8  __attribute__((ext_vector_type(8)));
typedef float  floatx4 __attribute__((ext_vector_type(4)));

#define AS1 __attribute__((address_space(1)))
#define AS3 __attribute__((address_space(3)))

__device__ __forceinline__ void async_copy16(const void* g, void* l) {
    __builtin_amdgcn_global_load_lds((const AS1 unsigned int*)g,
                                     (AS3 unsigned int*)l, 16, 0, 0);
}

__device__ __forceinline__ unsigned short f2bf(float f) {
    union { float f; unsigned int u; } v;
    v.f = f;
    unsigned int r = (v.u + 0x7fffu + ((v.u >> 16) & 1u)) >> 16;  // RNE
    return (unsigned short)r;
}

// --- fused prep: blocks [0,2048) convert x fp32->bf16 (contiguous lanes,
//     grid-stride); blocks [2048, ...) sparsify W (2:4 mask, stable-argsort
//     tie order) -> bf16. Single launch so its cost is visible in rocprof. --
#define CVT_BLOCKS 2048
__global__ __launch_bounds__(256) void cvt_sparsify(
    const float4* __restrict__ x, uint2* __restrict__ xb, long n4,
    const float4* __restrict__ W, unsigned long long* __restrict__ Wb,
    int ngroups) {
    if (blockIdx.x < CVT_BLOCKS) {
        const int lane = threadIdx.x & 63;
        const long wave   = ((long)blockIdx.x * 256 + threadIdx.x) >> 6;
        const long nwaves = (long)CVT_BLOCKS * 256 / 64;
        for (long base = wave * 128; base < n4; base += nwaves * 128) {
            const long i0 = base + lane;
            const long i1 = base + 64 + lane;
            float4 f0 = x[i0];
            float4 f1 = x[i1];
            uint2 o0, o1;
            o0.x = (unsigned)f2bf(f0.x) | ((unsigned)f2bf(f0.y) << 16);
            o0.y = (unsigned)f2bf(f0.z) | ((unsigned)f2bf(f0.w) << 16);
            o1.x = (unsigned)f2bf(f1.x) | ((unsigned)f2bf(f1.y) << 16);
            o1.y = (unsigned)f2bf(f1.z) | ((unsigned)f2bf(f1.w) << 16);
            xb[i0] = o0;
            xb[i1] = o1;
        }
    } else {
        const int g = (blockIdx.x - CVT_BLOCKS) * 256 + threadIdx.x;
        if (g >= ngroups) return;
        float4 w4 = W[g];
        float v[4] = {w4.x, w4.y, w4.z, w4.w};
        float a[4] = {fabsf(w4.x), fabsf(w4.y), fabsf(w4.z), fabsf(w4.w)};
        unsigned long long packed = 0;
#pragma unroll
        for (int i = 0; i < 4; i++) {
            int rank = 0;
#pragma unroll
            for (int j = 0; j < 4; j++)
                rank += (a[j] < a[i]) || (a[j] == a[i] && j < i);
            unsigned short b = (rank >= 2) ? f2bf(v[i]) : (unsigned short)0;
            packed |= ((unsigned long long)b) << (16 * i);
        }
        Wb[g] = packed;
    }
}

// --- bf16 B^T GEMM: 128x256 tile, BK=32, ring-3, 2 blocks/CU. ---------------
__global__ __launch_bounds__(256, 2) void gemm_bt_bf16_128x256(
    const unsigned short* __restrict__ A,   // [M,K] bf16
    const unsigned short* __restrict__ B,   // [N,K] bf16 (sparse W)
    const float* __restrict__ bias,         // [N]
    float* __restrict__ C,                  // [M,N] fp32
    int M, int N, int K) {
    __shared__ unsigned short lA[3][128 * 32];   // 3 x 8 KiB
    __shared__ unsigned short lB[3][256 * 32];   // 3 x 16 KiB  -> 72 KiB total

    const int tid  = threadIdx.x;
    const int w    = tid >> 6;       // wave 0..3 = N-quarter
    const int lane = tid & 63;

    // XCD-ownership mapping: 8 N-blocks == 8 XCDs (HW round-robins id&7).
    const int id  = blockIdx.x;
    const int nbx = N >> 8;
    int bm, bn;
    if (nbx == 8) {
        bn = (id & 7) << 8;
        bm = (id >> 3) << 7;
    } else {
        bn = (id % nbx) << 8;
        bm = (id / nbx) << 7;
    }

    // ---- staging addressing (global_load_lds, 16B/lane, LDS linear dest) ----
    // Swizzle: LDS[r][c8] = global[r][c8 ^ ((r>>1)&3)]; per 16-row instr the
    // row term collapses: source chunk = (L&3) ^ ((L>>3)&3).
    const int srow = lane >> 2;
    const int csw  = ((lane & 3) ^ ((lane >> 3) & 3)) * 8;   // bf16 elems
    const unsigned short* Ag0 = A + (size_t)(bm + w * 32 + srow) * K + csw;
    const unsigned short* Ag1 = Ag0 + (size_t)16 * K;
    const unsigned short* Bg0 = B + (size_t)(bn + w * 64 + srow) * K + csw;
    const unsigned short* Bg1 = Bg0 + (size_t)16 * K;
    const unsigned short* Bg2 = Bg0 + (size_t)32 * K;
    const unsigned short* Bg3 = Bg0 + (size_t)48 * K;
    const int wAa = w * 1024;         // A slab: rows [32w,32w+32), 32 elem rows
    const int wAb = w * 2048;         // B slab: rows [64w,64w+64)

    // ---- fragment read addressing (ds_read_b128) ----------------------------
    const int fm   = lane & 15;
    const int q    = lane >> 4;
    const int rch  = (q ^ ((fm >> 1) & 3)) * 8;
    const int aoff = fm * 32 + rch;              // + i*512 for row-block i
    const int boff = (w * 64 + fm) * 32 + rch;   // + j*512

    floatx4 acc[8][4];
#pragma unroll
    for (int i = 0; i < 8; i++)
#pragma unroll
        for (int j = 0; j < 4; j++)
            acc[i][j] = (floatx4){0.f, 0.f, 0.f, 0.f};

    const int NT = K >> 5;            // 64 K-tiles (requires NT >= 2)

#define STAGE_A(t, b)                                                    \
    {                                                                    \
        const size_t k0 = (size_t)(t) << 5;                              \
        async_copy16(Ag0 + k0, &lA[(b)][wAa]);                           \
        async_copy16(Ag1 + k0, &lA[(b)][wAa + 512]);                     \
    }
#define STAGE_B(t, b)                                                    \
    {                                                                    \
        const size_t k0 = (size_t)(t) << 5;                              \
        async_copy16(Bg0 + k0, &lB[(b)][wAb]);                           \
        async_copy16(Bg1 + k0, &lB[(b)][wAb + 512]);                     \
        async_copy16(Bg2 + k0, &lB[(b)][wAb + 1024]);                    \
        async_copy16(Bg3 + k0, &lB[(b)][wAb + 1536]);                    \
    }
#define BAR()                                                            \
    {                                                                    \
        asm volatile("" ::: "memory");                                   \
        __builtin_amdgcn_s_barrier();                                    \
        asm volatile("" ::: "memory");                                   \
    }

    // prologue: 2 tiles in flight (issue order = tile order for vmcnt count)
    STAGE_A(0, 0); STAGE_B(0, 0);
    STAGE_A(1, 1); STAGE_B(1, 1);
    asm volatile("s_waitcnt vmcnt(6)" ::: "memory");  // tile 0 landed
    BAR();                                            // rendezvous for tile 0

    int cur = 0;
    for (int t = 0; t < NT; ++t) {
        const int b  = cur;
        const int b2 = (cur + 2 >= 3) ? cur - 1 : cur + 2;   // (t+2)%3
        const bool st = (t + 2) < NT;

        bf16x8 aF[8], bF[4];

        // ---- phase 0: a rows 0-3 + all b (8 reads) ∥ stage A(t+2) ----------
#pragma unroll
        for (int i = 0; i < 4; i++)
            aF[i] = *(const bf16x8*)&lA[b][aoff + i * 512];
#pragma unroll
        for (int j = 0; j < 4; j++)
            bF[j] = *(const bf16x8*)&lB[b][boff + j * 512];
        if (st) STAGE_A(t + 2, b2);
        BAR();
        asm volatile("s_waitcnt lgkmcnt(0)" ::: "memory");
        __builtin_amdgcn_s_setprio(1);
#pragma unroll
        for (int i = 0; i < 4; i++)
#pragma unroll
            for (int j = 0; j < 4; j++)
                acc[i][j] = __builtin_amdgcn_mfma_f32_16x16x32_bf16(
                    aF[i], bF[j], acc[i][j], 0, 0, 0);
        __builtin_amdgcn_s_setprio(0);
        BAR();

        // ---- phase 1: a rows 4-7 (4 reads) ∥ stage B(t+2), counted vmcnt ---
#pragma unroll
        for (int i = 0; i < 4; i++)
            aF[4 + i] = *(const bf16x8*)&lA[b][aoff + (4 + i) * 512];
        if (st) STAGE_B(t + 2, b2);
        // outstanding: t+1 (6) + t+2 (6 if staged); complete t+1, keep t+2.
        if (t < NT - 2) asm volatile("s_waitcnt vmcnt(6)" ::: "memory");
        else            asm volatile("s_waitcnt vmcnt(0)" ::: "memory");
        BAR();
        asm volatile("s_waitcnt lgkmcnt(0)" ::: "memory");
        __builtin_amdgcn_s_setprio(1);
#pragma unroll
        for (int i = 0; i < 4; i++)
#pragma unroll
            for (int j = 0; j < 4; j++)
                acc[4 + i][j] = __builtin_amdgcn_mfma_f32_16x16x32_bf16(
                    aF[4 + i], bF[j], acc[4 + i][j], 0, 0, 0);
        __builtin_amdgcn_s_setprio(0);
        BAR();   // end barrier = rendezvous for tile t+1's reads

        cur = (cur + 1 >= 3) ? 0 : cur + 1;
    }

#undef STAGE_A
#undef STAGE_B
#undef BAR

    // epilogue: C/D layout col=lane&15, row=(lane>>4)*4+reg (m89-verified)
    const int cn  = lane & 15;
    const int cm4 = (lane >> 4) * 4;
#pragma unroll
    for (int j = 0; j < 4; j++) {
        const int col = bn + w * 64 + j * 16 + cn;
        const float bv = bias[col];
#pragma unroll
        for (int i = 0; i < 8; i++) {
            const size_t rbase = (size_t)(bm + i * 16 + cm4) * N + col;
#pragma unroll
            for (int r = 0; r < 4; r++)
                C[rbase + (size_t)r * N] = acc[i][j][r] + bv;
        }
    }
}

extern "C" void kernel_launch(void* const* d_in, const int* in_sizes, int n_in,
                              void* d_out, int out_size, void* d_ws, size_t ws_size,
                              hipStream_t stream) {
    const float* x    = (const float*)d_in[0];   // [S,B,H] fp32
    const float* w    = (const float*)d_in[1];   // [O,H]  fp32
    const float* bias = (const float*)d_in[2];   // [O]    fp32
    float* out = (float*)d_out;

    const int O = in_sizes[2];
    const int H = in_sizes[1] / O;
    const long M = (long)in_sizes[0] / H;        // S*B = 16384

    unsigned short* xb = (unsigned short*)d_ws;            // [M*H] bf16
    unsigned short* wb = xb + (size_t)M * H;               // [O*H] bf16

    const long n4 = (long)M * H / 4;
    const int ng = O * H / 4;
    const int prep_blocks = CVT_BLOCKS + (ng + 255) / 256;
    cvt_sparsify<<<dim3(prep_blocks), dim3(256), 0, stream>>>(
        (const float4*)x, (uint2*)xb, n4,
        (const float4*)w, (unsigned long long*)wb, ng);

    const int nblocks = (int)((M / 128) * ((long)O / 256));   // 1024, 1D grid
    gemm_bt_bf16_128x256<<<dim3(nblocks), dim3(256), 0, stream>>>(
        xb, wb, bias, out, (int)M, O, H);
}

// Round 5
// 379.048 us; speedup vs baseline: 1.0131x; 1.0131x over previous
//
#include <hip/hip_runtime.h>
#include <stdint.h>

// ---------------------------------------------------------------------------
// RowParallelLinearSparse: out[M,N] = x[M,K] · (W ⊙ nm_mask(W))[N,K]^T + bias
// M=16384 (S*B), N=O=2048, K=H=2048.  bf16 MFMA.
//
// GEMM v5: 256x256 tile, BK=64, 8 waves, dbuf LDS split into Mhalf/Nhalf
// units (128 KiB), 4 phases/K-tile = C-quadrant walk (mh,nh) = (0,0),(0,1),
// (1,1),(1,0); reads/phase 12,4,8,0.  WAVE OUTPUT STRADDLES ALL QUADRANTS
// (wave (wr,wc): rows mh*128+wr*64+[0,63], cols nh*128+wc*32+[0,31]) so each
// phase touches exactly one A-half + one B-half -> per-half vmcnt ledger is
// sound (v4's race: fixed slabs needed all 4 halves at ph1).
//
// vmcnt ledger (2 loads/half; stage during tile t for t+1: A0@ph1, B0@ph2,
// B1@ph3, A1@ph4; in-order retirement; checkpoints keep 2 newest halves):
//   end-ph4(t-1) vmcnt(4): drains A0(t),B0(t)  -> ph1 reads A0,B0   OK
//   end-ph1(t)   vmcnt(4): drains B1(t)        -> ph2 reads B1      OK
//   end-ph2(t)   vmcnt(4): drains A1(t)        -> ph3 reads A1      OK
//   ph4: no reads.  Tail t=NT-1: vmcnt(2)/(0) at ph1/ph2.  NT >= 2.
// WAR: stage into buf^1 half H >= 4 barriers after last ds_read of H(t-1).
// XOR swizzle: LDS[r][c8] = global[r][c8 ^ (r&7)] (source chunk collapses to
// (L&7)^(L>>3) for 8-row-aligned slabs); read chunk = (ks*4+q) ^ (fm&7).
// ---------------------------------------------------------------------------

typedef short  bf16x8  __attribute__((ext_vector_type(8)));
typedef float  floatx4 __attribute__((ext_vector_type(4)));

#define AS1 __attribute__((address_space(1)))
#define AS3 __attribute__((address_space(3)))

__device__ __forceinline__ void async_copy16(const void* g, void* l) {
    __builtin_amdgcn_global_load_lds((const AS1 unsigned int*)g,
                                     (AS3 unsigned int*)l, 16, 0, 0);
}

__device__ __forceinline__ unsigned short f2bf(float f) {
    union { float f; unsigned int u; } v;
    v.f = f;
    unsigned int r = (v.u + 0x7fffu + ((v.u >> 16) & 1u)) >> 16;  // RNE
    return (unsigned short)r;
}

// --- fused prep: blocks [0,2048) convert x fp32->bf16 (contiguous lanes,
//     grid-stride); blocks [2048,...) sparsify W (2:4, stable-argsort ties).
#define CVT_BLOCKS 2048
__global__ __launch_bounds__(256) void cvt_sparsify(
    const float4* __restrict__ x, uint2* __restrict__ xb, long n4,
    const float4* __restrict__ W, unsigned long long* __restrict__ Wb,
    int ngroups) {
    if (blockIdx.x < CVT_BLOCKS) {
        const int lane = threadIdx.x & 63;
        const long wave   = ((long)blockIdx.x * 256 + threadIdx.x) >> 6;
        const long nwaves = (long)CVT_BLOCKS * 256 / 64;
        for (long base = wave * 128; base < n4; base += nwaves * 128) {
            const long i0 = base + lane;
            const long i1 = base + 64 + lane;
            float4 f0 = x[i0];
            float4 f1 = x[i1];
            uint2 o0, o1;
            o0.x = (unsigned)f2bf(f0.x) | ((unsigned)f2bf(f0.y) << 16);
            o0.y = (unsigned)f2bf(f0.z) | ((unsigned)f2bf(f0.w) << 16);
            o1.x = (unsigned)f2bf(f1.x) | ((unsigned)f2bf(f1.y) << 16);
            o1.y = (unsigned)f2bf(f1.z) | ((unsigned)f2bf(f1.w) << 16);
            xb[i0] = o0;
            xb[i1] = o1;
        }
    } else {
        const int g = (blockIdx.x - CVT_BLOCKS) * 256 + threadIdx.x;
        if (g >= ngroups) return;
        float4 w4 = W[g];
        float v[4] = {w4.x, w4.y, w4.z, w4.w};
        float a[4] = {fabsf(w4.x), fabsf(w4.y), fabsf(w4.z), fabsf(w4.w)};
        unsigned long long packed = 0;
#pragma unroll
        for (int i = 0; i < 4; i++) {
            int rank = 0;
#pragma unroll
            for (int j = 0; j < 4; j++)
                rank += (a[j] < a[i]) || (a[j] == a[i] && j < i);
            unsigned short b = (rank >= 2) ? f2bf(v[i]) : (unsigned short)0;
            packed |= ((unsigned long long)b) << (16 * i);
        }
        Wb[g] = packed;
    }
}

// --- bf16 B^T GEMM: 256x256, BK=64, dbuf halves, straddled quadrant walk. ---
__global__ __launch_bounds__(512, 2) void gemm_bt_bf16_v5(
    const unsigned short* __restrict__ A,   // [M,K] bf16
    const unsigned short* __restrict__ B,   // [N,K] bf16 (sparse W)
    const float* __restrict__ bias,         // [N]
    float* __restrict__ C,                  // [M,N] fp32
    int M, int N, int K) {
    __shared__ unsigned short lA[2][2][128 * 64];   // [dbuf][Mhalf] 64 KiB
    __shared__ unsigned short lB[2][2][128 * 64];   // [dbuf][Nhalf] 64 KiB

    const int tid  = threadIdx.x;
    const int w    = tid >> 6;       // wave 0..7
    const int lane = tid & 63;
    const int wr   = w >> 2;         // 0..1
    const int wc   = w & 3;          // 0..3

    const int id  = blockIdx.x;
    const int nbx = N >> 8;
    int bm, bn;
    if (nbx == 8) {                  // XCD-ownership (HW round-robins id&7)
        bn = (id & 7) << 8;
        bm = (id >> 3) << 8;
    } else {
        bn = (id % nbx) << 8;
        bm = (id / nbx) << 8;
    }

    // ---- staging (global_load_lds 16B/lane, linear LDS dest) ---------------
    const int sr8 = lane >> 3;                       // 0..7
    const int scw = ((lane & 7) ^ sr8) * 8;          // pre-swizzled source col
    const unsigned short* Agp = A + (size_t)(bm + w * 8 + sr8) * K + scw;
    const unsigned short* Bgp = B + (size_t)(bn + w * 8 + sr8) * K + scw;
    const int sl = w * 512;          // wave's 8-row slab within a half (elems)

    // ---- fragment reads (ds_read_b128) -------------------------------------
    const int fm   = lane & 15;
    const int q    = lane >> 4;
    const int x0   = (q ^ (fm & 7)) * 8;             // ks=0; ks=1 -> x0 ^ 32
    const int arow = (wr * 64 + fm) * 64;            // + ii*1024, in half-array
    const int brow = (wc * 32 + fm) * 64;            // + jj*1024

    floatx4 acc[8][4];
#pragma unroll
    for (int i = 0; i < 8; i++)
#pragma unroll
        for (int j = 0; j < 4; j++)
            acc[i][j] = (floatx4){0.f, 0.f, 0.f, 0.f};

    const int NT = K >> 6;            // 32 K-tiles (requires NT >= 2)

#define STG_A(t, bf, mh)                                                  \
    {                                                                     \
        const size_t k0 = (size_t)(t) << 6;                               \
        async_copy16(Agp + (size_t)((mh) * 128) * K + k0,                 \
                     &lA[bf][mh][sl]);                                    \
        async_copy16(Agp + (size_t)((mh) * 128 + 64) * K + k0,            \
                     &lA[bf][mh][sl + 4096]);                             \
    }
#define STG_B(t, bf, nh)                                                  \
    {                                                                     \
        const size_t k0 = (size_t)(t) << 6;                               \
        async_copy16(Bgp + (size_t)((nh) * 128) * K + k0,                 \
                     &lB[bf][nh][sl]);                                    \
        async_copy16(Bgp + (size_t)((nh) * 128 + 64) * K + k0,            \
                     &lB[bf][nh][sl + 4096]);                             \
    }
#define BAR()                                                             \
    {                                                                     \
        asm volatile("" ::: "memory");                                    \
        __builtin_amdgcn_s_barrier();                                     \
        asm volatile("" ::: "memory");                                    \
    }

    // prologue: stage tile 0 in ledger order A0,B0,B1,A1
    STG_A(0, 0, 0);
    STG_B(0, 0, 0);
    STG_B(0, 0, 1);
    STG_A(0, 0, 1);
    asm volatile("s_waitcnt vmcnt(4)" ::: "memory");  // A0,B0 landed
    BAR();

    bf16x8 aF[4][2], bF[4][2];

    for (int t = 0; t < NT; ++t) {
        const int  b  = t & 1;
        const bool st = (t + 1) < NT;

        // ---- ph1 (mh0,nh0): read A0 (8) + B j0..1 (4) ∥ stage A0(t+1) ------
#pragma unroll
        for (int ii = 0; ii < 4; ii++) {
            aF[ii][0] = *(const bf16x8*)&lA[b][0][arow + ii * 1024 + x0];
            aF[ii][1] = *(const bf16x8*)&lA[b][0][arow + ii * 1024 + (x0 ^ 32)];
        }
#pragma unroll
        for (int jj = 0; jj < 2; jj++) {
            bF[jj][0] = *(const bf16x8*)&lB[b][0][brow + jj * 1024 + x0];
            bF[jj][1] = *(const bf16x8*)&lB[b][0][brow + jj * 1024 + (x0 ^ 32)];
        }
        if (st) STG_A(t + 1, b ^ 1, 0);
        asm volatile("s_waitcnt lgkmcnt(8)" ::: "memory");
        BAR();
        asm volatile("s_waitcnt lgkmcnt(0)" ::: "memory");
        __builtin_amdgcn_s_setprio(1);
#pragma unroll
        for (int ks = 0; ks < 2; ks++)
#pragma unroll
            for (int ii = 0; ii < 4; ii++)
#pragma unroll
                for (int jj = 0; jj < 2; jj++)
                    acc[ii][jj] = __builtin_amdgcn_mfma_f32_16x16x32_bf16(
                        aF[ii][ks], bF[jj][ks], acc[ii][jj], 0, 0, 0);
        __builtin_amdgcn_s_setprio(0);
        if (st) { asm volatile("s_waitcnt vmcnt(4)" ::: "memory"); }
        else    { asm volatile("s_waitcnt vmcnt(2)" ::: "memory"); }
        BAR();

        // ---- ph2 (mh0,nh1): read B j2..3 (4) ∥ stage B0(t+1) ---------------
#pragma unroll
        for (int jj = 0; jj < 2; jj++) {
            bF[2 + jj][0] = *(const bf16x8*)&lB[b][1][brow + jj * 1024 + x0];
            bF[2 + jj][1] = *(const bf16x8*)&lB[b][1][brow + jj * 1024 + (x0 ^ 32)];
        }
        if (st) STG_B(t + 1, b ^ 1, 0);
        BAR();
        asm volatile("s_waitcnt lgkmcnt(0)" ::: "memory");
        __builtin_amdgcn_s_setprio(1);
#pragma unroll
        for (int ks = 0; ks < 2; ks++)
#pragma unroll
            for (int ii = 0; ii < 4; ii++)
#pragma unroll
                for (int jj = 0; jj < 2; jj++)
                    acc[ii][2 + jj] = __builtin_amdgcn_mfma_f32_16x16x32_bf16(
                        aF[ii][ks], bF[2 + jj][ks], acc[ii][2 + jj], 0, 0, 0);
        __builtin_amdgcn_s_setprio(0);
        if (st) { asm volatile("s_waitcnt vmcnt(4)" ::: "memory"); }
        else    { asm volatile("s_waitcnt vmcnt(0)" ::: "memory"); }
        BAR();

        // ---- ph3 (mh1,nh1): read A1 (8, reuse regs) ∥ stage B1(t+1) --------
#pragma unroll
        for (int ii = 0; ii < 4; ii++) {
            aF[ii][0] = *(const bf16x8*)&lA[b][1][arow + ii * 1024 + x0];
            aF[ii][1] = *(const bf16x8*)&lA[b][1][arow + ii * 1024 + (x0 ^ 32)];
        }
        if (st) STG_B(t + 1, b ^ 1, 1);
        BAR();
        asm volatile("s_waitcnt lgkmcnt(0)" ::: "memory");
        __builtin_amdgcn_s_setprio(1);
#pragma unroll
        for (int ks = 0; ks < 2; ks++)
#pragma unroll
            for (int ii = 0; ii < 4; ii++)
#pragma unroll
                for (int jj = 0; jj < 2; jj++)
                    acc[4 + ii][2 + jj] = __builtin_amdgcn_mfma_f32_16x16x32_bf16(
                        aF[ii][ks], bF[2 + jj][ks], acc[4 + ii][2 + jj], 0, 0, 0);
        __builtin_amdgcn_s_setprio(0);
        BAR();

        // ---- ph4 (mh1,nh0): no reads ∥ stage A1(t+1) -----------------------
        if (st) STG_A(t + 1, b ^ 1, 1);
        __builtin_amdgcn_s_setprio(1);
#pragma unroll
        for (int ks = 0; ks < 2; ks++)
#pragma unroll
            for (int ii = 0; ii < 4; ii++)
#pragma unroll
                for (int jj = 0; jj < 2; jj++)
                    acc[4 + ii][jj] = __builtin_amdgcn_mfma_f32_16x16x32_bf16(
                        aF[ii][ks], bF[jj][ks], acc[4 + ii][jj], 0, 0, 0);
        __builtin_amdgcn_s_setprio(0);
        if (st) { asm volatile("s_waitcnt vmcnt(4)" ::: "memory"); }
        BAR();
    }

#undef STG_A
#undef STG_B
#undef BAR

    // epilogue: C/D layout col=lane&15, row=(lane>>4)*4+reg (m89-verified).
    // Straddled map: row = bm + (i>>2)*128 + wr*64 + (i&3)*16 + cm4 + r,
    //                col = bn + (j>>1)*128 + wc*32 + (j&1)*16 + cn.
    const int cn  = lane & 15;
    const int cm4 = (lane >> 4) * 4;
#pragma unroll
    for (int j = 0; j < 4; j++) {
        const int col = bn + (j >> 1) * 128 + wc * 32 + (j & 1) * 16 + cn;
        const float bv = bias[col];
#pragma unroll
        for (int i = 0; i < 8; i++) {
            const size_t rbase =
                (size_t)(bm + (i >> 2) * 128 + wr * 64 + (i & 3) * 16 + cm4) * N
                + col;
#pragma unroll
            for (int r = 0; r < 4; r++)
                C[rbase + (size_t)r * N] = acc[i][j][r] + bv;
        }
    }
}

extern "C" void kernel_launch(void* const* d_in, const int* in_sizes, int n_in,
                              void* d_out, int out_size, void* d_ws, size_t ws_size,
                              hipStream_t stream) {
    const float* x    = (const float*)d_in[0];   // [S,B,H] fp32
    const float* w    = (const float*)d_in[1];   // [O,H]  fp32
    const float* bias = (const float*)d_in[2];   // [O]    fp32
    float* out = (float*)d_out;

    const int O = in_sizes[2];
    const int H = in_sizes[1] / O;
    const long M = (long)in_sizes[0] / H;        // S*B = 16384

    unsigned short* xb = (unsigned short*)d_ws;            // [M*H] bf16
    unsigned short* wb = xb + (size_t)M * H;               // [O*H] bf16

    const long n4 = (long)M * H / 4;
    const int ng = O * H / 4;
    const int prep_blocks = CVT_BLOCKS + (ng + 255) / 256;
    cvt_sparsify<<<dim3(prep_blocks), dim3(256), 0, stream>>>(
        (const float4*)x, (uint2*)xb, n4,
        (const float4*)w, (unsigned long long*)wb, ng);

    const int nblocks = (int)((M / 256) * ((long)O / 256));   // 512, 1D grid
    gemm_bt_bf16_v5<<<dim3(nblocks), dim3(512), 0, stream>>>(
        xb, wb, bias, out, (int)M, O, H);
}